// Round 9
// baseline (148.565 us; speedup 1.0000x reference)
//
#include <hip/hip_runtime.h>

// Problem constants
#define NNODES 64
#define HID 32
#define NFACT 3
#define NE 1024
#define NROWS (NE + NFACT)   // 1027
#define TPB 256
#define STR 36               // row stride (floats) for xpp/qp
#define MAXTILES 128         // capacity bound (true max = 124)

// d_ws int layout: [0]=ntiles  [64..127]=deg[n]  [128..255]=tile_node[t]  [256..]=pep[t*16+i]
//   pep packed: low16 = edge id (0xFFFF = pad), high16 = dst node (0 for pad)
#define WS_DEG  64
#define WS_TN   128
#define WS_PE   256

typedef short bf16x8 __attribute__((ext_vector_type(8)));
typedef float f32x4  __attribute__((ext_vector_type(4)));

// round-to-nearest-even two fp32 -> packed bf16x2 (lo | hi<<16)
__device__ __forceinline__ unsigned pack_bf2(float lo, float hi) {
    unsigned ul = __builtin_bit_cast(unsigned, lo);
    unsigned uh = __builtin_bit_cast(unsigned, hi);
    ul += 0x7fffu + ((ul >> 16) & 1u);
    uh += 0x7fffu + ((uh >> 16) & 1u);
    return (ul >> 16) | (uh & 0xffff0000u);
}
__device__ __forceinline__ short f2bf(float f) {
    unsigned u = __builtin_bit_cast(unsigned, f);
    u += 0x7fffu + ((u >> 16) & 1u);
    return (short)(u >> 16);
}
__device__ __forceinline__ float4 fma4(float a, float4 w, float4 c) {
    c.x = fmaf(a, w.x, c.x); c.y = fmaf(a, w.y, c.y);
    c.z = fmaf(a, w.z, c.z); c.w = fmaf(a, w.w, c.w);
    return c;
}

// ---- Kernel 0: CSR of edges grouped by src, 16-edge tiles, dst packed in ----
__global__ __launch_bounds__(TPB) void build_csr(const int* __restrict__ es,
                                                 const int* __restrict__ ed,
                                                 int* __restrict__ ws) {
    __shared__ int sdeg[NNODES], soff[NNODES], scnt[NNODES];
    const int tid = threadIdx.x;
    if (tid < NNODES) { sdeg[tid] = 0; scnt[tid] = 0; }
    if (tid < MAXTILES) ws[WS_TN + tid] = 0;
#pragma unroll 1
    for (int i = tid; i < MAXTILES * 16; i += TPB) ws[WS_PE + i] = 0xFFFF;
    __syncthreads();
#pragma unroll 1
    for (int e = tid; e < NE; e += TPB) atomicAdd(&sdeg[es[e]], 1);
    __syncthreads();
    if (tid == 0) {
        int run = 0;
#pragma unroll 1
        for (int n = 0; n < NNODES; n++) { soff[n] = run; run += (sdeg[n] + 15) >> 4; }
        ws[0] = run;   // dynamic tile count (~90-96 typical, <=124)
    }
    __syncthreads();
    if (tid < NNODES) {
        ws[WS_DEG + tid] = sdeg[tid];
        const int base = soff[tid], cnt = (sdeg[tid] + 15) >> 4;
#pragma unroll 1
        for (int j = 0; j < cnt; j++) ws[WS_TN + base + j] = tid;
    }
    __syncthreads();
#pragma unroll 1
    for (int e = tid; e < NE; e += TPB) {
        const int n = es[e];
        const int idx = atomicAdd(&scnt[n], 1);
        ws[WS_PE + soff[n] * 16 + idx] = e | (ed[e] << 16);
    }
}

// ---- Kernel 1: fused per-graph critic; MFMA for both edge-GEMM and head projection ----
__global__ __launch_bounds__(TPB, 5) void critic_fused(
    const float* __restrict__ x,
    const float* __restrict__ edge_attr,
    const float* __restrict__ action,
    const int*   __restrict__ es,
    const int*   __restrict__ ed,
    const float* __restrict__ W1,
    const float* __restrict__ b1,
    const float* __restrict__ W2,
    const float* __restrict__ b2,
    const float* __restrict__ Wl,
    const float* __restrict__ bl,
    const float* __restrict__ Wv,
    const float* __restrict__ bv,
    const int*   __restrict__ csr,
    float* __restrict__ out)
{
    const int b    = blockIdx.x;
    const int tid  = threadIdx.x;
    const int lane = tid & 63;
    const int wv   = tid >> 6;
    const int quad = lane >> 4;
    const int m16  = lane & 15;
    const int kh   = quad * 8;

    __shared__ float4 xs4[NNODES];
    __shared__ float  xpp[NNODES * STR];
    __shared__ float  qp0[NNODES * STR];      // Q1 then P1
    __shared__ float  qp1[NNODES * STR];      // Q2 then P2
    __shared__ float  W1s[10 * HID];
    __shared__ float  b1s[HID];
    __shared__ float  wred[TPB / 64];

    // ---- Stage A: stage x + W1 (LDS), zero xpp ----
    if (tid < NNODES) xs4[tid] = ((const float4*)x)[b * NNODES + tid];
    if (tid < 80) ((float4*)W1s)[tid] = ((const float4*)W1)[tid];
    if (tid < HID) b1s[tid] = b1[tid];
#pragma unroll 1
    for (int i = tid; i < NNODES * STR; i += TPB) xpp[i] = 0.0f;

    // ---- Stage-P constants: registers, loaded from global early (hidden under Q/B) ----
    bf16x8 bP1a, bP1b, bP2a, bP2b;    // Wl[4:36] / Wl[40:72] B-fragments, col halves
#pragma unroll
    for (int j = 0; j < 8; j++) {
        bP1a[j] = f2bf(Wl[(4 + kh + j) * HID + m16]);
        bP1b[j] = f2bf(Wl[(4 + kh + j) * HID + 16 + m16]);
        bP2a[j] = f2bf(Wl[(40 + kh + j) * HID + m16]);
        bP2b[j] = f2bf(Wl[(40 + kh + j) * HID + 16 + m16]);
    }
    float wx1a[4], wx1b[4], wx2a[4], wx2b[4];   // x-part weights (K=4 tail)
#pragma unroll
    for (int i = 0; i < 4; i++) {
        wx1a[i] = Wl[i * HID + m16];
        wx1b[i] = Wl[i * HID + 16 + m16];
        wx2a[i] = Wl[(36 + i) * HID + m16];
        wx2b[i] = Wl[(36 + i) * HID + 16 + m16];
    }
    const float blca = bl[m16], blcb = bl[16 + m16];
    float b2k[8];
#pragma unroll
    for (int j = 0; j < 8; j++) b2k[j] = b2[kh + j];
    const int   mrow = wv * 16 + m16;                // A-row this lane owns in stage P
    const float dn   = (float)csr[WS_DEG + mrow];
    __syncthreads();

    const int n  = tid & 63;
    const int k0 = (tid >> 6) * 8;

    // ---- Stage Q: per-node first-layer partials ----
    {
        const float4 xv = xs4[n];
        const float4* b1v = (const float4*)&b1s[k0];
        float4 q1a = b1v[0], q1b = b1v[1];
        float4 q2a = make_float4(0.f, 0.f, 0.f, 0.f), q2b = q2a;
#pragma unroll 1
        for (int i = 0; i < 4; i++) {
            const float xi = (i == 0) ? xv.x : (i == 1) ? xv.y : (i == 2) ? xv.z : xv.w;
            const float4* wa = (const float4*)&W1s[i * HID + k0];
            const float4* wb = (const float4*)&W1s[(4 + i) * HID + k0];
            q1a = fma4(xi, wa[0], q1a); q1b = fma4(xi, wa[1], q1b);
            q2a = fma4(xi, wb[0], q2a); q2b = fma4(xi, wb[1], q2b);
        }
        float4* q1w = (float4*)&qp0[n * STR + k0];
        float4* q2w = (float4*)&qp1[n * STR + k0];
        q1w[0] = q1a; q1w[1] = q1b;
        q2w[0] = q2a; q2w[1] = q2b;
    }
    __syncthreads();

    // ---- Stage B: CSR-tiled MFMA edge messages (dynamic tile count) ----
    {
        const float2* ea2 = (const float2*)edge_attr + (size_t)b * NE;
        const int NW = TPB / 64;

        const float4* w8p = (const float4*)&W1s[8 * HID + kh];
        const float4* w9p = (const float4*)&W1s[9 * HID + kh];
        const float4 w8a = w8p[0], w8b = w8p[1];
        const float4 w9a = w9p[0], w9b = w9p[1];

        bf16x8 bf0, bf1;   // W2 B-fragments (column halves)
#pragma unroll
        for (int j = 0; j < 8; j++) {
            bf0[j] = f2bf(W2[(kh + j) * HID + m16]);
            bf1[j] = f2bf(W2[(kh + j) * HID + 16 + m16]);
        }

        const int  ntiles = csr[0];
        const int* tn  = csr + WS_TN;
        const int* pep = csr + WS_PE;

#pragma unroll 1
        for (int t = wv; t < ntiles; t += NW) {
            const int raw  = pep[t * 16 + m16];
            const int node = tn[t];                    // wave-uniform
            const int e    = raw & 0xFFFF;
            const bool pad = (e == 0xFFFF);
            const int d0   = raw >> 16;                // dst node (0 for pad)
            const float2 ea = ea2[pad ? 0 : e];

            const float4* Ap = (const float4*)&qp0[node * STR + kh];  // broadcast
            const float4  A0 = Ap[0], A1 = Ap[1];
            const float4* Gp = (const float4*)&qp1[d0 * STR + kh];    // gather
            const float4  G0 = Gp[0], G1 = Gp[1];

            const float h0 = fmaxf(A0.x + G0.x + ea.x * w8a.x + ea.y * w9a.x, 0.f);
            const float h1 = fmaxf(A0.y + G0.y + ea.x * w8a.y + ea.y * w9a.y, 0.f);
            const float h2 = fmaxf(A0.z + G0.z + ea.x * w8a.z + ea.y * w9a.z, 0.f);
            const float h3 = fmaxf(A0.w + G0.w + ea.x * w8a.w + ea.y * w9a.w, 0.f);
            const float h4 = fmaxf(A1.x + G1.x + ea.x * w8b.x + ea.y * w9b.x, 0.f);
            const float h5 = fmaxf(A1.y + G1.y + ea.x * w8b.y + ea.y * w9b.y, 0.f);
            const float h6 = fmaxf(A1.z + G1.z + ea.x * w8b.z + ea.y * w9b.z, 0.f);
            const float h7 = fmaxf(A1.w + G1.w + ea.x * w8b.w + ea.y * w9b.w, 0.f);

            uint4 packed;
            packed.x = pad ? 0u : pack_bf2(h0, h1);
            packed.y = pad ? 0u : pack_bf2(h2, h3);
            packed.z = pad ? 0u : pack_bf2(h4, h5);
            packed.w = pad ? 0u : pack_bf2(h6, h7);
            const bf16x8 af = __builtin_bit_cast(bf16x8, packed);

            f32x4 c0 = {0.f, 0.f, 0.f, 0.f};
            f32x4 c1 = {0.f, 0.f, 0.f, 0.f};
            c0 = __builtin_amdgcn_mfma_f32_16x16x32_bf16(af, bf0, c0, 0, 0, 0);
            c1 = __builtin_amdgcn_mfma_f32_16x16x32_bf16(af, bf1, c1, 0, 0, 0);

            // all 16 rows target `node`: reduce rows -> column totals
            float s0 = c0[0] + c0[1] + c0[2] + c0[3];
            float s1 = c1[0] + c1[1] + c1[2] + c1[3];
            s0 += __shfl_xor(s0, 16); s0 += __shfl_xor(s0, 32);
            s1 += __shfl_xor(s1, 16); s1 += __shfl_xor(s1, 32);
            if (lane < 32)
                atomicAdd(&xpp[node * STR + lane], (lane < 16) ? s0 : s1);
        }
    }
    __syncthreads();

    // ---- Stage P: head projections via MFMA ----
    // A (16x32) = bf16(xpp[mtile] + deg*b2); B = Wl fragments (registers);
    // x-part (K=4) + bias folded into C-operand.
    {
        const float4* xr = (const float4*)&xpp[mrow * STR + kh];
        float4 x0 = xr[0], x1 = xr[1];
        x0.x = fmaf(dn, b2k[0], x0.x); x0.y = fmaf(dn, b2k[1], x0.y);
        x0.z = fmaf(dn, b2k[2], x0.z); x0.w = fmaf(dn, b2k[3], x0.w);
        x1.x = fmaf(dn, b2k[4], x1.x); x1.y = fmaf(dn, b2k[5], x1.y);
        x1.z = fmaf(dn, b2k[6], x1.z); x1.w = fmaf(dn, b2k[7], x1.w);
        uint4 packed;
        packed.x = pack_bf2(x0.x, x0.y);
        packed.y = pack_bf2(x0.z, x0.w);
        packed.z = pack_bf2(x1.x, x1.y);
        packed.w = pack_bf2(x1.z, x1.w);
        const bf16x8 af = __builtin_bit_cast(bf16x8, packed);

        f32x4 c1a, c1b, c2a, c2b;
#pragma unroll
        for (int r = 0; r < 4; r++) {
            const float4 xv = xs4[wv * 16 + quad * 4 + r];
            float a0 = blca, a1 = blcb, a2 = 0.f, a3 = 0.f;
#pragma unroll
            for (int i = 0; i < 4; i++) {
                const float xi = (i == 0) ? xv.x : (i == 1) ? xv.y : (i == 2) ? xv.z : xv.w;
                a0 = fmaf(xi, wx1a[i], a0);
                a1 = fmaf(xi, wx1b[i], a1);
                a2 = fmaf(xi, wx2a[i], a2);
                a3 = fmaf(xi, wx2b[i], a3);
            }
            c1a[r] = a0; c1b[r] = a1; c2a[r] = a2; c2b[r] = a3;
        }
        c1a = __builtin_amdgcn_mfma_f32_16x16x32_bf16(af, bP1a, c1a, 0, 0, 0);
        c1b = __builtin_amdgcn_mfma_f32_16x16x32_bf16(af, bP1b, c1b, 0, 0, 0);
        c2a = __builtin_amdgcn_mfma_f32_16x16x32_bf16(af, bP2a, c2a, 0, 0, 0);
        c2b = __builtin_amdgcn_mfma_f32_16x16x32_bf16(af, bP2b, c2b, 0, 0, 0);

        // C layout: row = wv*16 + quad*4 + r, col = m16 / 16+m16
#pragma unroll
        for (int r = 0; r < 4; r++) {
            const int row = wv * 16 + quad * 4 + r;
            qp0[row * STR + m16]      = c1a[r];
            qp0[row * STR + 16 + m16] = c1b[r];
            qp1[row * STR + m16]      = c2a[r];
            qp1[row * STR + 16 + m16] = c2b[r];
        }
    }
    __syncthreads();

    // ---- Stage C: per-row combine + value head ----
    float vsum = 0.0f;
    {
        const float* actb = action + (size_t)b * NROWS;
        const float bvv = bv[0];
        const float* Wl72 = Wl + 72 * HID;   // loop-invariant s_loads, hoisted
#pragma unroll 1
        for (int i = 0; i < 4; i++) {
            const int r = tid + i * TPB;
            const int na = es[r], nb = ed[r];
            const float a = actb[r];
            const float4* p1v = (const float4*)&qp0[na * STR];
            const float4* p2v = (const float4*)&qp1[nb * STR];
            float v0 = bvv, v1 = 0.0f;
#pragma unroll 1
            for (int q = 0; q < 8; q += 2) {
                const float4 pa0 = p1v[q],     pb0 = p2v[q];
                const float4 pa1 = p1v[q + 1], pb1 = p2v[q + 1];
                const int k = q * 4;
                v0 += fmaxf(pa0.x + pb0.x + a * Wl72[k+0], 0.f) * Wv[k+0];
                v1 += fmaxf(pa0.y + pb0.y + a * Wl72[k+1], 0.f) * Wv[k+1];
                v0 += fmaxf(pa0.z + pb0.z + a * Wl72[k+2], 0.f) * Wv[k+2];
                v1 += fmaxf(pa0.w + pb0.w + a * Wl72[k+3], 0.f) * Wv[k+3];
                v0 += fmaxf(pa1.x + pb1.x + a * Wl72[k+4], 0.f) * Wv[k+4];
                v1 += fmaxf(pa1.y + pb1.y + a * Wl72[k+5], 0.f) * Wv[k+5];
                v0 += fmaxf(pa1.z + pb1.z + a * Wl72[k+6], 0.f) * Wv[k+6];
                v1 += fmaxf(pa1.w + pb1.w + a * Wl72[k+7], 0.f) * Wv[k+7];
            }
            vsum += v0 + v1;
        }
        // factory rows 1024..1026 (na == nb)
        if (tid < NFACT) {
            const int r = NE + tid;
            const int na = NNODES - NFACT + tid;
            const float a = actb[r];
            const float4* p1v = (const float4*)&qp0[na * STR];
            const float4* p2v = (const float4*)&qp1[na * STR];
            float v = bvv;
#pragma unroll 1
            for (int q = 0; q < 8; q++) {
                const float4 pa = p1v[q], pb = p2v[q];
                const int k = q * 4;
                v += fmaxf(pa.x + pb.x + a * Wl72[k+0], 0.f) * Wv[k+0];
                v += fmaxf(pa.y + pb.y + a * Wl72[k+1], 0.f) * Wv[k+1];
                v += fmaxf(pa.z + pb.z + a * Wl72[k+2], 0.f) * Wv[k+2];
                v += fmaxf(pa.w + pb.w + a * Wl72[k+3], 0.f) * Wv[k+3];
            }
            vsum += v;
        }
    }

    // ---- block reduction ----
#pragma unroll
    for (int off = 32; off > 0; off >>= 1)
        vsum += __shfl_down(vsum, off, 64);
    if ((tid & 63) == 0) wred[tid >> 6] = vsum;
    __syncthreads();
    if (tid == 0) {
        float t = 0.0f;
#pragma unroll
        for (int w = 0; w < TPB / 64; w++) t += wred[w];
        out[b] = t;
    }
}

extern "C" void kernel_launch(void* const* d_in, const int* in_sizes, int n_in,
                              void* d_out, int out_size, void* d_ws, size_t ws_size,
                              hipStream_t stream) {
    const float* x         = (const float*)d_in[0];
    const float* edge_attr = (const float*)d_in[2];
    const float* action    = (const float*)d_in[3];
    const int*   es        = (const int*)d_in[4];
    const int*   ed        = (const int*)d_in[5];
    const float* W1        = (const float*)d_in[6];
    const float* b1        = (const float*)d_in[7];
    const float* W2        = (const float*)d_in[8];
    const float* b2        = (const float*)d_in[9];
    const float* Wl        = (const float*)d_in[10];
    const float* bl        = (const float*)d_in[11];
    const float* Wv        = (const float*)d_in[12];
    const float* bv        = (const float*)d_in[13];
    float* out = (float*)d_out;
    int*   ws  = (int*)d_ws;

    build_csr<<<dim3(1), dim3(TPB), 0, stream>>>(es, ed, ws);
    critic_fused<<<dim3(out_size), dim3(TPB), 0, stream>>>(
        x, edge_attr, action, es, ed, W1, b1, W2, b2, Wl, bl, Wv, bv, ws, out);
}

// Round 10
// 137.503 us; speedup vs baseline: 1.0805x; 1.0805x over previous
//
#include <hip/hip_runtime.h>

// Problem constants
#define NNODES 64
#define HID 32
#define NFACT 3
#define NE 1024
#define NROWS (NE + NFACT)   // 1027
#define TPB 256
#define STR 36               // row stride (floats) for xpp/qp
#define MAXTILES 128         // capacity bound (true max = 124)

// d_ws int layout: [0]=ntiles  [64..127]=deg[n]  [128..255]=tile_node[t]  [256..]=pep[t*16+i]
//   pep packed: low16 = edge id (0xFFFF = pad), high16 = dst node (0 for pad)
#define WS_DEG  64
#define WS_TN   128
#define WS_PE   256

typedef short bf16x8 __attribute__((ext_vector_type(8)));
typedef float f32x4  __attribute__((ext_vector_type(4)));

// round-to-nearest-even two fp32 -> packed bf16x2 (lo | hi<<16)
__device__ __forceinline__ unsigned pack_bf2(float lo, float hi) {
    unsigned ul = __builtin_bit_cast(unsigned, lo);
    unsigned uh = __builtin_bit_cast(unsigned, hi);
    ul += 0x7fffu + ((ul >> 16) & 1u);
    uh += 0x7fffu + ((uh >> 16) & 1u);
    return (ul >> 16) | (uh & 0xffff0000u);
}
__device__ __forceinline__ short f2bf(float f) {
    unsigned u = __builtin_bit_cast(unsigned, f);
    u += 0x7fffu + ((u >> 16) & 1u);
    return (short)(u >> 16);
}
__device__ __forceinline__ float4 fma4(float a, float4 w, float4 c) {
    c.x = fmaf(a, w.x, c.x); c.y = fmaf(a, w.y, c.y);
    c.z = fmaf(a, w.z, c.z); c.w = fmaf(a, w.w, c.w);
    return c;
}

// ---- Kernel 0: CSR of edges grouped by src, 16-edge tiles, dst packed in ----
__global__ __launch_bounds__(TPB) void build_csr(const int* __restrict__ es,
                                                 const int* __restrict__ ed,
                                                 int* __restrict__ ws) {
    __shared__ int sdeg[NNODES], soff[NNODES], scnt[NNODES];
    const int tid = threadIdx.x;
    if (tid < NNODES) { sdeg[tid] = 0; scnt[tid] = 0; }
    if (tid < MAXTILES) ws[WS_TN + tid] = 0;
#pragma unroll 1
    for (int i = tid; i < MAXTILES * 16; i += TPB) ws[WS_PE + i] = 0xFFFF;
    __syncthreads();
#pragma unroll 1
    for (int e = tid; e < NE; e += TPB) atomicAdd(&sdeg[es[e]], 1);
    __syncthreads();
    if (tid == 0) {
        int run = 0;
#pragma unroll 1
        for (int n = 0; n < NNODES; n++) { soff[n] = run; run += (sdeg[n] + 15) >> 4; }
        ws[0] = run;   // dynamic tile count (~90-96 typical, <=124)
    }
    __syncthreads();
    if (tid < NNODES) {
        ws[WS_DEG + tid] = sdeg[tid];
        const int base = soff[tid], cnt = (sdeg[tid] + 15) >> 4;
#pragma unroll 1
        for (int j = 0; j < cnt; j++) ws[WS_TN + base + j] = tid;
    }
    __syncthreads();
#pragma unroll 1
    for (int e = tid; e < NE; e += TPB) {
        const int n = es[e];
        const int idx = atomicAdd(&scnt[n], 1);
        ws[WS_PE + soff[n] * 16 + idx] = e | (ed[e] << 16);
    }
}

// ---- Kernel 1: fused per-graph critic; MFMA for edge-GEMM and head projection ----
// launch_bounds (256,4): 128-VGPR budget. (256,5) spilled ~25 KB/block scratch (R9).
__global__ __launch_bounds__(TPB, 4) void critic_fused(
    const float* __restrict__ x,
    const float* __restrict__ edge_attr,
    const float* __restrict__ action,
    const int*   __restrict__ es,
    const int*   __restrict__ ed,
    const float* __restrict__ W1,
    const float* __restrict__ b1,
    const float* __restrict__ W2,
    const float* __restrict__ b2,
    const float* __restrict__ Wl,
    const float* __restrict__ bl,
    const float* __restrict__ Wv,
    const float* __restrict__ bv,
    const int*   __restrict__ csr,
    float* __restrict__ out)
{
    const int b    = blockIdx.x;
    const int tid  = threadIdx.x;
    const int lane = tid & 63;
    const int wv   = tid >> 6;
    const int quad = lane >> 4;
    const int m16  = lane & 15;
    const int kh   = quad * 8;

    __shared__ float4 xs4[NNODES];
    __shared__ float  xpp[NNODES * STR];
    __shared__ float  qp0[NNODES * STR];      // Q1 then P1
    __shared__ float  qp1[NNODES * STR];      // Q2 then P2
    __shared__ float  W1s[10 * HID];
    __shared__ float  b1s[HID];
    __shared__ float  wred[TPB / 64];

    // ---- Stage A: stage x + W1 (LDS), zero xpp ----
    if (tid < NNODES) xs4[tid] = ((const float4*)x)[b * NNODES + tid];
    if (tid < 80) ((float4*)W1s)[tid] = ((const float4*)W1)[tid];
    if (tid < HID) b1s[tid] = b1[tid];
#pragma unroll 1
    for (int i = tid; i < NNODES * STR; i += TPB) xpp[i] = 0.0f;
    __syncthreads();

    const int n  = tid & 63;
    const int k0 = (tid >> 6) * 8;

    // ---- Stage Q: per-node first-layer partials ----
    {
        const float4 xv = xs4[n];
        const float4* b1v = (const float4*)&b1s[k0];
        float4 q1a = b1v[0], q1b = b1v[1];
        float4 q2a = make_float4(0.f, 0.f, 0.f, 0.f), q2b = q2a;
#pragma unroll 1
        for (int i = 0; i < 4; i++) {
            const float xi = (i == 0) ? xv.x : (i == 1) ? xv.y : (i == 2) ? xv.z : xv.w;
            const float4* wa = (const float4*)&W1s[i * HID + k0];
            const float4* wb = (const float4*)&W1s[(4 + i) * HID + k0];
            q1a = fma4(xi, wa[0], q1a); q1b = fma4(xi, wa[1], q1b);
            q2a = fma4(xi, wb[0], q2a); q2b = fma4(xi, wb[1], q2b);
        }
        float4* q1w = (float4*)&qp0[n * STR + k0];
        float4* q2w = (float4*)&qp1[n * STR + k0];
        q1w[0] = q1a; q1w[1] = q1b;
        q2w[0] = q2a; q2w[1] = q2b;
    }

    // ---- Stage-P constants: per-lane global loads issued here so they overlap stage B ----
    bf16x8 bP1a, bP1b, bP2a, bP2b;    // Wl[4:36] / Wl[40:72] B-fragments, col halves
#pragma unroll
    for (int j = 0; j < 8; j++) {
        bP1a[j] = f2bf(Wl[(4 + kh + j) * HID + m16]);
        bP1b[j] = f2bf(Wl[(4 + kh + j) * HID + 16 + m16]);
        bP2a[j] = f2bf(Wl[(40 + kh + j) * HID + m16]);
        bP2b[j] = f2bf(Wl[(40 + kh + j) * HID + 16 + m16]);
    }
    float wx1a[4], wx1b[4], wx2a[4], wx2b[4];   // x-part weights (K=4 tail)
#pragma unroll
    for (int i = 0; i < 4; i++) {
        wx1a[i] = Wl[i * HID + m16];
        wx1b[i] = Wl[i * HID + 16 + m16];
        wx2a[i] = Wl[(36 + i) * HID + m16];
        wx2b[i] = Wl[(36 + i) * HID + 16 + m16];
    }
    const float blca = bl[m16], blcb = bl[16 + m16];
    float b2k[8];
#pragma unroll
    for (int j = 0; j < 8; j++) b2k[j] = b2[kh + j];
    const int   mrow = wv * 16 + m16;                // A-row this lane owns in stage P
    const float dn   = (float)csr[WS_DEG + mrow];
    __syncthreads();

    // ---- Stage B: CSR-tiled MFMA edge messages (dynamic tile count) ----
    {
        const float2* ea2 = (const float2*)edge_attr + (size_t)b * NE;
        const int NW = TPB / 64;

        const float4* w8p = (const float4*)&W1s[8 * HID + kh];
        const float4* w9p = (const float4*)&W1s[9 * HID + kh];
        const float4 w8a = w8p[0], w8b = w8p[1];
        const float4 w9a = w9p[0], w9b = w9p[1];

        bf16x8 bf0, bf1;   // W2 B-fragments (column halves)
#pragma unroll
        for (int j = 0; j < 8; j++) {
            bf0[j] = f2bf(W2[(kh + j) * HID + m16]);
            bf1[j] = f2bf(W2[(kh + j) * HID + 16 + m16]);
        }

        const int  ntiles = csr[0];
        const int* tn  = csr + WS_TN;
        const int* pep = csr + WS_PE;

#pragma unroll 1
        for (int t = wv; t < ntiles; t += NW) {
            const int raw  = pep[t * 16 + m16];
            const int node = tn[t];                    // wave-uniform
            const int e    = raw & 0xFFFF;
            const bool pad = (e == 0xFFFF);
            const int d0   = raw >> 16;                // dst node (0 for pad)
            const float2 ea = ea2[pad ? 0 : e];

            const float4* Ap = (const float4*)&qp0[node * STR + kh];  // broadcast
            const float4  A0 = Ap[0], A1 = Ap[1];
            const float4* Gp = (const float4*)&qp1[d0 * STR + kh];    // gather
            const float4  G0 = Gp[0], G1 = Gp[1];

            const float h0 = fmaxf(A0.x + G0.x + ea.x * w8a.x + ea.y * w9a.x, 0.f);
            const float h1 = fmaxf(A0.y + G0.y + ea.x * w8a.y + ea.y * w9a.y, 0.f);
            const float h2 = fmaxf(A0.z + G0.z + ea.x * w8a.z + ea.y * w9a.z, 0.f);
            const float h3 = fmaxf(A0.w + G0.w + ea.x * w8a.w + ea.y * w9a.w, 0.f);
            const float h4 = fmaxf(A1.x + G1.x + ea.x * w8b.x + ea.y * w9b.x, 0.f);
            const float h5 = fmaxf(A1.y + G1.y + ea.x * w8b.y + ea.y * w9b.y, 0.f);
            const float h6 = fmaxf(A1.z + G1.z + ea.x * w8b.z + ea.y * w9b.z, 0.f);
            const float h7 = fmaxf(A1.w + G1.w + ea.x * w8b.w + ea.y * w9b.w, 0.f);

            uint4 packed;
            packed.x = pad ? 0u : pack_bf2(h0, h1);
            packed.y = pad ? 0u : pack_bf2(h2, h3);
            packed.z = pad ? 0u : pack_bf2(h4, h5);
            packed.w = pad ? 0u : pack_bf2(h6, h7);
            const bf16x8 af = __builtin_bit_cast(bf16x8, packed);

            f32x4 c0 = {0.f, 0.f, 0.f, 0.f};
            f32x4 c1 = {0.f, 0.f, 0.f, 0.f};
            c0 = __builtin_amdgcn_mfma_f32_16x16x32_bf16(af, bf0, c0, 0, 0, 0);
            c1 = __builtin_amdgcn_mfma_f32_16x16x32_bf16(af, bf1, c1, 0, 0, 0);

            // all 16 rows target `node`: reduce rows -> column totals
            float s0 = c0[0] + c0[1] + c0[2] + c0[3];
            float s1 = c1[0] + c1[1] + c1[2] + c1[3];
            s0 += __shfl_xor(s0, 16); s0 += __shfl_xor(s0, 32);
            s1 += __shfl_xor(s1, 16); s1 += __shfl_xor(s1, 32);
            if (lane < 32)
                atomicAdd(&xpp[node * STR + lane], (lane < 16) ? s0 : s1);
        }
    }
    __syncthreads();

    // ---- Stage P: head projections via MFMA ----
    // A (16x32) = bf16(xpp[mrow] + deg*b2); B = Wl fragments (registers);
    // x-part (K=4) + bias folded into C-operand.
    {
        const float4* xr = (const float4*)&xpp[mrow * STR + kh];
        float4 x0 = xr[0], x1 = xr[1];
        x0.x = fmaf(dn, b2k[0], x0.x); x0.y = fmaf(dn, b2k[1], x0.y);
        x0.z = fmaf(dn, b2k[2], x0.z); x0.w = fmaf(dn, b2k[3], x0.w);
        x1.x = fmaf(dn, b2k[4], x1.x); x1.y = fmaf(dn, b2k[5], x1.y);
        x1.z = fmaf(dn, b2k[6], x1.z); x1.w = fmaf(dn, b2k[7], x1.w);
        uint4 packed;
        packed.x = pack_bf2(x0.x, x0.y);
        packed.y = pack_bf2(x0.z, x0.w);
        packed.z = pack_bf2(x1.x, x1.y);
        packed.w = pack_bf2(x1.z, x1.w);
        const bf16x8 af = __builtin_bit_cast(bf16x8, packed);

        f32x4 c1a, c1b, c2a, c2b;
#pragma unroll
        for (int r = 0; r < 4; r++) {
            const float4 xv = xs4[wv * 16 + quad * 4 + r];
            float a0 = blca, a1 = blcb, a2 = 0.f, a3 = 0.f;
#pragma unroll
            for (int i = 0; i < 4; i++) {
                const float xi = (i == 0) ? xv.x : (i == 1) ? xv.y : (i == 2) ? xv.z : xv.w;
                a0 = fmaf(xi, wx1a[i], a0);
                a1 = fmaf(xi, wx1b[i], a1);
                a2 = fmaf(xi, wx2a[i], a2);
                a3 = fmaf(xi, wx2b[i], a3);
            }
            c1a[r] = a0; c1b[r] = a1; c2a[r] = a2; c2b[r] = a3;
        }
        c1a = __builtin_amdgcn_mfma_f32_16x16x32_bf16(af, bP1a, c1a, 0, 0, 0);
        c1b = __builtin_amdgcn_mfma_f32_16x16x32_bf16(af, bP1b, c1b, 0, 0, 0);
        c2a = __builtin_amdgcn_mfma_f32_16x16x32_bf16(af, bP2a, c2a, 0, 0, 0);
        c2b = __builtin_amdgcn_mfma_f32_16x16x32_bf16(af, bP2b, c2b, 0, 0, 0);

        // C layout: row = wv*16 + quad*4 + r, col = m16 / 16+m16
#pragma unroll
        for (int r = 0; r < 4; r++) {
            const int row = wv * 16 + quad * 4 + r;
            qp0[row * STR + m16]      = c1a[r];
            qp0[row * STR + 16 + m16] = c1b[r];
            qp1[row * STR + m16]      = c2a[r];
            qp1[row * STR + 16 + m16] = c2b[r];
        }
    }
    __syncthreads();

    // ---- Stage C: per-row combine + value head ----
    float vsum = 0.0f;
    {
        const float* actb = action + (size_t)b * NROWS;
        const float bvv = bv[0];
        const float* Wl72 = Wl + 72 * HID;   // loop-invariant s_loads, hoisted
#pragma unroll 1
        for (int i = 0; i < 4; i++) {
            const int r = tid + i * TPB;
            const int na = es[r], nb = ed[r];
            const float a = actb[r];
            const float4* p1v = (const float4*)&qp0[na * STR];
            const float4* p2v = (const float4*)&qp1[nb * STR];
            float v0 = bvv, v1 = 0.0f;
#pragma unroll 1
            for (int q = 0; q < 8; q += 2) {
                const float4 pa0 = p1v[q],     pb0 = p2v[q];
                const float4 pa1 = p1v[q + 1], pb1 = p2v[q + 1];
                const int k = q * 4;
                v0 += fmaxf(pa0.x + pb0.x + a * Wl72[k+0], 0.f) * Wv[k+0];
                v1 += fmaxf(pa0.y + pb0.y + a * Wl72[k+1], 0.f) * Wv[k+1];
                v0 += fmaxf(pa0.z + pb0.z + a * Wl72[k+2], 0.f) * Wv[k+2];
                v1 += fmaxf(pa0.w + pb0.w + a * Wl72[k+3], 0.f) * Wv[k+3];
                v0 += fmaxf(pa1.x + pb1.x + a * Wl72[k+4], 0.f) * Wv[k+4];
                v1 += fmaxf(pa1.y + pb1.y + a * Wl72[k+5], 0.f) * Wv[k+5];
                v0 += fmaxf(pa1.z + pb1.z + a * Wl72[k+6], 0.f) * Wv[k+6];
                v1 += fmaxf(pa1.w + pb1.w + a * Wl72[k+7], 0.f) * Wv[k+7];
            }
            vsum += v0 + v1;
        }
        // factory rows 1024..1026 (na == nb)
        if (tid < NFACT) {
            const int r = NE + tid;
            const int na = NNODES - NFACT + tid;
            const float a = actb[r];
            const float4* p1v = (const float4*)&qp0[na * STR];
            const float4* p2v = (const float4*)&qp1[na * STR];
            float v = bvv;
#pragma unroll 1
            for (int q = 0; q < 8; q++) {
                const float4 pa = p1v[q], pb = p2v[q];
                const int k = q * 4;
                v += fmaxf(pa.x + pb.x + a * Wl72[k+0], 0.f) * Wv[k+0];
                v += fmaxf(pa.y + pb.y + a * Wl72[k+1], 0.f) * Wv[k+1];
                v += fmaxf(pa.z + pb.z + a * Wl72[k+2], 0.f) * Wv[k+2];
                v += fmaxf(pa.w + pb.w + a * Wl72[k+3], 0.f) * Wv[k+3];
            }
            vsum += v;
        }
    }

    // ---- block reduction ----
#pragma unroll
    for (int off = 32; off > 0; off >>= 1)
        vsum += __shfl_down(vsum, off, 64);
    if ((tid & 63) == 0) wred[tid >> 6] = vsum;
    __syncthreads();
    if (tid == 0) {
        float t = 0.0f;
#pragma unroll
        for (int w = 0; w < TPB / 64; w++) t += wred[w];
        out[b] = t;
    }
}

extern "C" void kernel_launch(void* const* d_in, const int* in_sizes, int n_in,
                              void* d_out, int out_size, void* d_ws, size_t ws_size,
                              hipStream_t stream) {
    const float* x         = (const float*)d_in[0];
    const float* edge_attr = (const float*)d_in[2];
    const float* action    = (const float*)d_in[3];
    const int*   es        = (const int*)d_in[4];
    const int*   ed        = (const int*)d_in[5];
    const float* W1        = (const float*)d_in[6];
    const float* b1        = (const float*)d_in[7];
    const float* W2        = (const float*)d_in[8];
    const float* b2        = (const float*)d_in[9];
    const float* Wl        = (const float*)d_in[10];
    const float* bl        = (const float*)d_in[11];
    const float* Wv        = (const float*)d_in[12];
    const float* bv        = (const float*)d_in[13];
    float* out = (float*)d_out;
    int*   ws  = (int*)d_ws;

    build_csr<<<dim3(1), dim3(TPB), 0, stream>>>(es, ed, ws);
    critic_fused<<<dim3(out_size), dim3(TPB), 0, stream>>>(
        x, edge_attr, action, es, ed, W1, b1, W2, b2, Wl, bl, Wv, bv, ws, out);
}

// Round 11
// 132.134 us; speedup vs baseline: 1.1244x; 1.0406x over previous
//
#include <hip/hip_runtime.h>

// Problem constants
#define NNODES 64
#define HID 32
#define NFACT 3
#define NE 1024
#define NROWS (NE + NFACT)   // 1027
#define TPB 256
#define STR 36               // row stride (floats) for xpp/qp
#define MAXTILES 128         // capacity bound (true max = 124)

// d_ws int layout: [0]=ntiles  [64..127]=deg[n]  [128..255]=tile_node[t]  [256..]=pep[t*16+i]
//   pep packed: low12 = edge id (0xFFF = pad), bits12-17 = dst node, bits18-23 = src (tile) node
#define WS_DEG  64
#define WS_TN   128
#define WS_PE   256

typedef short bf16x8 __attribute__((ext_vector_type(8)));
typedef float f32x4  __attribute__((ext_vector_type(4)));
typedef float f32x16 __attribute__((ext_vector_type(16)));

// round-to-nearest-even two fp32 -> packed bf16x2 (lo | hi<<16)
__device__ __forceinline__ unsigned pack_bf2(float lo, float hi) {
    unsigned ul = __builtin_bit_cast(unsigned, lo);
    unsigned uh = __builtin_bit_cast(unsigned, hi);
    ul += 0x7fffu + ((ul >> 16) & 1u);
    uh += 0x7fffu + ((uh >> 16) & 1u);
    return (ul >> 16) | (uh & 0xffff0000u);
}
__device__ __forceinline__ short f2bf(float f) {
    unsigned u = __builtin_bit_cast(unsigned, f);
    u += 0x7fffu + ((u >> 16) & 1u);
    return (short)(u >> 16);
}
__device__ __forceinline__ float4 fma4(float a, float4 w, float4 c) {
    c.x = fmaf(a, w.x, c.x); c.y = fmaf(a, w.y, c.y);
    c.z = fmaf(a, w.z, c.z); c.w = fmaf(a, w.w, c.w);
    return c;
}

// ---- Kernel 0: CSR of edges grouped by src, 16-edge tiles; src/dst packed in ----
__global__ __launch_bounds__(TPB) void build_csr(const int* __restrict__ es,
                                                 const int* __restrict__ ed,
                                                 int* __restrict__ ws) {
    __shared__ int sdeg[NNODES], soff[NNODES], scnt[NNODES];
    const int tid = threadIdx.x;
    if (tid < NNODES) { sdeg[tid] = 0; scnt[tid] = 0; }
    if (tid < MAXTILES) ws[WS_TN + tid] = 0;
#pragma unroll 1
    for (int i = tid; i < MAXTILES * 16; i += TPB) ws[WS_PE + i] = 0xFFF;  // pad, node 0
    __syncthreads();
#pragma unroll 1
    for (int e = tid; e < NE; e += TPB) atomicAdd(&sdeg[es[e]], 1);
    __syncthreads();
    if (tid < NNODES) {   // wave 0: shuffle prefix-scan of ceil(deg/16)
        const int cnt = (sdeg[tid] + 15) >> 4;
        int scan = cnt;
#pragma unroll
        for (int o = 1; o < 64; o <<= 1) {
            const int v = __shfl_up(scan, o);
            if (tid >= o) scan += v;
        }
        soff[tid] = scan - cnt;
        ws[WS_DEG + tid] = sdeg[tid];
        if (tid == NNODES - 1) ws[0] = scan;    // ntiles (~90-96, <=124)
    }
    __syncthreads();
    if (tid < NNODES) {
        const int base = soff[tid], cnt = (sdeg[tid] + 15) >> 4;
        const int padv = 0xFFF | (tid << 18);   // pads carry the tile's node
#pragma unroll 1
        for (int j = 0; j < cnt; j++) {
            ws[WS_TN + base + j] = tid;
#pragma unroll 1
            for (int s = 0; s < 16; s++) ws[WS_PE + (base + j) * 16 + s] = padv;
        }
    }
    __syncthreads();
#pragma unroll 1
    for (int e = tid; e < NE; e += TPB) {
        const int n = es[e];
        const int idx = atomicAdd(&scnt[n], 1);
        ws[WS_PE + soff[n] * 16 + idx] = e | (ed[e] << 12) | (n << 18);
    }
}

// ---- Kernel 1: fused per-graph critic; MFMA edge-GEMM (pair-tiled 32x32x16) + MFMA head ----
__global__ __launch_bounds__(TPB, 4) void critic_fused(
    const float* __restrict__ x,
    const float* __restrict__ edge_attr,
    const float* __restrict__ action,
    const int*   __restrict__ es,
    const int*   __restrict__ ed,
    const float* __restrict__ W1,
    const float* __restrict__ b1,
    const float* __restrict__ W2,
    const float* __restrict__ b2,
    const float* __restrict__ Wl,
    const float* __restrict__ bl,
    const float* __restrict__ Wv,
    const float* __restrict__ bv,
    const int*   __restrict__ csr,
    float* __restrict__ out)
{
    const int b    = blockIdx.x;
    const int tid  = threadIdx.x;
    const int lane = tid & 63;
    const int wv   = tid >> 6;
    const int quad = lane >> 4;
    const int m16  = lane & 15;
    const int kh   = quad * 8;

    __shared__ float4 xs4[NNODES];
    __shared__ float  xpp[NNODES * STR];
    __shared__ float  qp0[NNODES * STR];      // Q1 then P1
    __shared__ float  qp1[NNODES * STR];      // Q2 then P2
    __shared__ float  W1s[10 * HID];
    __shared__ float  b1s[HID];
    __shared__ float  wred[TPB / 64];

    // ---- Stage A: stage x + W1 (LDS), zero xpp ----
    if (tid < NNODES) xs4[tid] = ((const float4*)x)[b * NNODES + tid];
    if (tid < 80) ((float4*)W1s)[tid] = ((const float4*)W1)[tid];
    if (tid < HID) b1s[tid] = b1[tid];
#pragma unroll 1
    for (int i = tid; i < NNODES * STR; i += TPB) xpp[i] = 0.0f;
    __syncthreads();

    const int n  = tid & 63;
    const int k0 = (tid >> 6) * 8;

    // ---- Stage Q: per-node first-layer partials ----
    {
        const float4 xv = xs4[n];
        const float4* b1v = (const float4*)&b1s[k0];
        float4 q1a = b1v[0], q1b = b1v[1];
        float4 q2a = make_float4(0.f, 0.f, 0.f, 0.f), q2b = q2a;
#pragma unroll 1
        for (int i = 0; i < 4; i++) {
            const float xi = (i == 0) ? xv.x : (i == 1) ? xv.y : (i == 2) ? xv.z : xv.w;
            const float4* wa = (const float4*)&W1s[i * HID + k0];
            const float4* wb = (const float4*)&W1s[(4 + i) * HID + k0];
            q1a = fma4(xi, wa[0], q1a); q1b = fma4(xi, wa[1], q1b);
            q2a = fma4(xi, wb[0], q2a); q2b = fma4(xi, wb[1], q2b);
        }
        float4* q1w = (float4*)&qp0[n * STR + k0];
        float4* q2w = (float4*)&qp1[n * STR + k0];
        q1w[0] = q1a; q1w[1] = q1b;
        q2w[0] = q2a; q2w[1] = q2b;
    }
    __syncthreads();

    // ---- Stage B: pair-tiled MFMA edge messages (32 edges / 2 nodes per iteration) ----
    {
        const float2* ea2 = (const float2*)edge_attr + (size_t)b * NE;
        const int NW  = TPB / 64;
        const int klo = (lane >> 5) * 8;      // this lane's K-slice base (0 or 8)
        const int n32 = lane & 31;

        // W1 rows 8,9 at k = klo..klo+7 and 16+klo..16+klo+7 (lane-constant)
        const float4* w8l = (const float4*)&W1s[8 * HID + klo];
        const float4* w8h = (const float4*)&W1s[8 * HID + 16 + klo];
        const float4* w9l = (const float4*)&W1s[9 * HID + klo];
        const float4* w9h = (const float4*)&W1s[9 * HID + 16 + klo];
        const float4 w8a = w8l[0], w8b = w8l[1], w8c = w8h[0], w8d = w8h[1];
        const float4 w9a = w9l[0], w9b = w9l[1], w9c = w9h[0], w9d = w9h[1];

        bf16x8 bfA, bfB;   // W2 B-frags: B[k][n32], K-halves 0..15 / 16..31
#pragma unroll
        for (int j = 0; j < 8; j++) {
            bfA[j] = f2bf(W2[(klo + j) * HID + n32]);
            bfB[j] = f2bf(W2[(16 + klo + j) * HID + n32]);
        }

        const int  ntiles = csr[0];
        const int  np     = (ntiles + 1) >> 1;
        const int* tn  = csr + WS_TN;
        const int* pep = csr + WS_PE;

#pragma unroll 1
        for (int p = wv; p < np; p += NW) {
            const int raw = pep[p * 32 + n32];        // edge slot m = n32 of the pair
            const int tA  = tn[2 * p];
            const int tB  = tn[2 * p + 1];
            const int e    = raw & 0xFFF;
            const bool pad = (e == 0xFFF);
            const int d0   = (raw >> 12) & 63;
            const int nd   = (raw >> 18) & 63;        // src node of MY edge (gather)
            const float2 ea = ea2[pad ? 0 : e];

            const float4* A1 = (const float4*)&qp0[nd * STR + klo];
            const float4* A2 = (const float4*)&qp0[nd * STR + 16 + klo];
            const float4* G1 = (const float4*)&qp1[d0 * STR + klo];
            const float4* G2 = (const float4*)&qp1[d0 * STR + 16 + klo];
            const float4 a0 = A1[0], a1 = A1[1], a2 = A2[0], a3 = A2[1];
            const float4 g0 = G1[0], g1 = G1[1], g2 = G2[0], g3 = G2[1];

            // h1 for k = klo..klo+7 (lo half) and 16+klo..16+klo+7 (hi half)
            const float hx0 = fmaxf(a0.x + g0.x + ea.x * w8a.x + ea.y * w9a.x, 0.f);
            const float hx1 = fmaxf(a0.y + g0.y + ea.x * w8a.y + ea.y * w9a.y, 0.f);
            const float hx2 = fmaxf(a0.z + g0.z + ea.x * w8a.z + ea.y * w9a.z, 0.f);
            const float hx3 = fmaxf(a0.w + g0.w + ea.x * w8a.w + ea.y * w9a.w, 0.f);
            const float hx4 = fmaxf(a1.x + g1.x + ea.x * w8b.x + ea.y * w9b.x, 0.f);
            const float hx5 = fmaxf(a1.y + g1.y + ea.x * w8b.y + ea.y * w9b.y, 0.f);
            const float hx6 = fmaxf(a1.z + g1.z + ea.x * w8b.z + ea.y * w9b.z, 0.f);
            const float hx7 = fmaxf(a1.w + g1.w + ea.x * w8b.w + ea.y * w9b.w, 0.f);
            const float hy0 = fmaxf(a2.x + g2.x + ea.x * w8c.x + ea.y * w9c.x, 0.f);
            const float hy1 = fmaxf(a2.y + g2.y + ea.x * w8c.y + ea.y * w9c.y, 0.f);
            const float hy2 = fmaxf(a2.z + g2.z + ea.x * w8c.z + ea.y * w9c.z, 0.f);
            const float hy3 = fmaxf(a2.w + g2.w + ea.x * w8c.w + ea.y * w9c.w, 0.f);
            const float hy4 = fmaxf(a3.x + g3.x + ea.x * w8d.x + ea.y * w9d.x, 0.f);
            const float hy5 = fmaxf(a3.y + g3.y + ea.x * w8d.y + ea.y * w9d.y, 0.f);
            const float hy6 = fmaxf(a3.z + g3.z + ea.x * w8d.z + ea.y * w9d.z, 0.f);
            const float hy7 = fmaxf(a3.w + g3.w + ea.x * w8d.w + ea.y * w9d.w, 0.f);

            uint4 pkA, pkB;
            pkA.x = pad ? 0u : pack_bf2(hx0, hx1);
            pkA.y = pad ? 0u : pack_bf2(hx2, hx3);
            pkA.z = pad ? 0u : pack_bf2(hx4, hx5);
            pkA.w = pad ? 0u : pack_bf2(hx6, hx7);
            pkB.x = pad ? 0u : pack_bf2(hy0, hy1);
            pkB.y = pad ? 0u : pack_bf2(hy2, hy3);
            pkB.z = pad ? 0u : pack_bf2(hy4, hy5);
            pkB.w = pad ? 0u : pack_bf2(hy6, hy7);
            const bf16x8 afA = __builtin_bit_cast(bf16x8, pkA);
            const bf16x8 afB = __builtin_bit_cast(bf16x8, pkB);

            f32x16 c;
#pragma unroll
            for (int j = 0; j < 16; j++) c[j] = 0.0f;
            c = __builtin_amdgcn_mfma_f32_32x32x16_bf16(afA, bfA, c, 0, 0, 0);
            c = __builtin_amdgcn_mfma_f32_32x32x16_bf16(afB, bfB, c, 0, 0, 0);

            // C: col=lane&31, row=(reg&3)+8*(reg>>2)+4*(lane>>5).
            // regs 0-7 -> rows 0-15 (tile A), regs 8-15 -> rows 16-31 (tile B).
            float sA = ((c[0] + c[1]) + (c[2] + c[3])) + ((c[4] + c[5]) + (c[6] + c[7]));
            float sB = ((c[8] + c[9]) + (c[10] + c[11])) + ((c[12] + c[13]) + (c[14] + c[15]));
            sA += __shfl_xor(sA, 32);
            sB += __shfl_xor(sB, 32);
            const int   nst = (lane < 32) ? tA : tB;
            const float sv  = (lane < 32) ? sA : sB;
            atomicAdd(&xpp[nst * STR + n32], sv);     // full wave, contiguous per node
        }
    }
    __syncthreads();

    // ---- Stage-P constants (loaded after B to keep stage-B VGPR peak low) ----
    bf16x8 bP1a, bP1b, bP2a, bP2b;    // Wl[4:36] / Wl[40:72] B-fragments, col halves
#pragma unroll
    for (int j = 0; j < 8; j++) {
        bP1a[j] = f2bf(Wl[(4 + kh + j) * HID + m16]);
        bP1b[j] = f2bf(Wl[(4 + kh + j) * HID + 16 + m16]);
        bP2a[j] = f2bf(Wl[(40 + kh + j) * HID + m16]);
        bP2b[j] = f2bf(Wl[(40 + kh + j) * HID + 16 + m16]);
    }
    float wx1a[4], wx1b[4], wx2a[4], wx2b[4];   // x-part weights (K=4 tail)
#pragma unroll
    for (int i = 0; i < 4; i++) {
        wx1a[i] = Wl[i * HID + m16];
        wx1b[i] = Wl[i * HID + 16 + m16];
        wx2a[i] = Wl[(36 + i) * HID + m16];
        wx2b[i] = Wl[(36 + i) * HID + 16 + m16];
    }
    const float blca = bl[m16], blcb = bl[16 + m16];
    float b2k[8];
#pragma unroll
    for (int j = 0; j < 8; j++) b2k[j] = b2[kh + j];
    const int   mrow = wv * 16 + m16;                // A-row this lane owns in stage P
    const float dn   = (float)csr[WS_DEG + mrow];

    // ---- Stage P: head projections via MFMA ----
    {
        const float4* xr = (const float4*)&xpp[mrow * STR + kh];
        float4 x0 = xr[0], x1 = xr[1];
        x0.x = fmaf(dn, b2k[0], x0.x); x0.y = fmaf(dn, b2k[1], x0.y);
        x0.z = fmaf(dn, b2k[2], x0.z); x0.w = fmaf(dn, b2k[3], x0.w);
        x1.x = fmaf(dn, b2k[4], x1.x); x1.y = fmaf(dn, b2k[5], x1.y);
        x1.z = fmaf(dn, b2k[6], x1.z); x1.w = fmaf(dn, b2k[7], x1.w);
        uint4 packed;
        packed.x = pack_bf2(x0.x, x0.y);
        packed.y = pack_bf2(x0.z, x0.w);
        packed.z = pack_bf2(x1.x, x1.y);
        packed.w = pack_bf2(x1.z, x1.w);
        const bf16x8 af = __builtin_bit_cast(bf16x8, packed);

        f32x4 c1a, c1b, c2a, c2b;
#pragma unroll
        for (int r = 0; r < 4; r++) {
            const float4 xv = xs4[wv * 16 + quad * 4 + r];
            float a0 = blca, a1 = blcb, a2 = 0.f, a3 = 0.f;
#pragma unroll
            for (int i = 0; i < 4; i++) {
                const float xi = (i == 0) ? xv.x : (i == 1) ? xv.y : (i == 2) ? xv.z : xv.w;
                a0 = fmaf(xi, wx1a[i], a0);
                a1 = fmaf(xi, wx1b[i], a1);
                a2 = fmaf(xi, wx2a[i], a2);
                a3 = fmaf(xi, wx2b[i], a3);
            }
            c1a[r] = a0; c1b[r] = a1; c2a[r] = a2; c2b[r] = a3;
        }
        c1a = __builtin_amdgcn_mfma_f32_16x16x32_bf16(af, bP1a, c1a, 0, 0, 0);
        c1b = __builtin_amdgcn_mfma_f32_16x16x32_bf16(af, bP1b, c1b, 0, 0, 0);
        c2a = __builtin_amdgcn_mfma_f32_16x16x32_bf16(af, bP2a, c2a, 0, 0, 0);
        c2b = __builtin_amdgcn_mfma_f32_16x16x32_bf16(af, bP2b, c2b, 0, 0, 0);

        // C layout: row = wv*16 + quad*4 + r, col = m16 / 16+m16
#pragma unroll
        for (int r = 0; r < 4; r++) {
            const int row = wv * 16 + quad * 4 + r;
            qp0[row * STR + m16]      = c1a[r];
            qp0[row * STR + 16 + m16] = c1b[r];
            qp1[row * STR + m16]      = c2a[r];
            qp1[row * STR + 16 + m16] = c2b[r];
        }
    }
    __syncthreads();

    // ---- Stage C: per-row combine + value head ----
    float vsum = 0.0f;
    {
        const float* actb = action + (size_t)b * NROWS;
        const float bvv = bv[0];
        const float* Wl72 = Wl + 72 * HID;   // loop-invariant s_loads, hoisted
#pragma unroll 1
        for (int i = 0; i < 4; i++) {
            const int r = tid + i * TPB;
            const int na = es[r], nb = ed[r];
            const float a = actb[r];
            const float4* p1v = (const float4*)&qp0[na * STR];
            const float4* p2v = (const float4*)&qp1[nb * STR];
            float v0 = bvv, v1 = 0.0f;
#pragma unroll 1
            for (int q = 0; q < 8; q += 2) {
                const float4 pa0 = p1v[q],     pb0 = p2v[q];
                const float4 pa1 = p1v[q + 1], pb1 = p2v[q + 1];
                const int k = q * 4;
                v0 += fmaxf(pa0.x + pb0.x + a * Wl72[k+0], 0.f) * Wv[k+0];
                v1 += fmaxf(pa0.y + pb0.y + a * Wl72[k+1], 0.f) * Wv[k+1];
                v0 += fmaxf(pa0.z + pb0.z + a * Wl72[k+2], 0.f) * Wv[k+2];
                v1 += fmaxf(pa0.w + pb0.w + a * Wl72[k+3], 0.f) * Wv[k+3];
                v0 += fmaxf(pa1.x + pb1.x + a * Wl72[k+4], 0.f) * Wv[k+4];
                v1 += fmaxf(pa1.y + pb1.y + a * Wl72[k+5], 0.f) * Wv[k+5];
                v0 += fmaxf(pa1.z + pb1.z + a * Wl72[k+6], 0.f) * Wv[k+6];
                v1 += fmaxf(pa1.w + pb1.w + a * Wl72[k+7], 0.f) * Wv[k+7];
            }
            vsum += v0 + v1;
        }
        // factory rows 1024..1026 (na == nb)
        if (tid < NFACT) {
            const int r = NE + tid;
            const int na = NNODES - NFACT + tid;
            const float a = actb[r];
            const float4* p1v = (const float4*)&qp0[na * STR];
            const float4* p2v = (const float4*)&qp1[na * STR];
            float v = bvv;
#pragma unroll 1
            for (int q = 0; q < 8; q++) {
                const float4 pa = p1v[q], pb = p2v[q];
                const int k = q * 4;
                v += fmaxf(pa.x + pb.x + a * Wl72[k+0], 0.f) * Wv[k+0];
                v += fmaxf(pa.y + pb.y + a * Wl72[k+1], 0.f) * Wv[k+1];
                v += fmaxf(pa.z + pb.z + a * Wl72[k+2], 0.f) * Wv[k+2];
                v += fmaxf(pa.w + pb.w + a * Wl72[k+3], 0.f) * Wv[k+3];
            }
            vsum += v;
        }
    }

    // ---- block reduction ----
#pragma unroll
    for (int off = 32; off > 0; off >>= 1)
        vsum += __shfl_down(vsum, off, 64);
    if ((tid & 63) == 0) wred[tid >> 6] = vsum;
    __syncthreads();
    if (tid == 0) {
        float t = 0.0f;
#pragma unroll
        for (int w = 0; w < TPB / 64; w++) t += wred[w];
        out[b] = t;
    }
}

extern "C" void kernel_launch(void* const* d_in, const int* in_sizes, int n_in,
                              void* d_out, int out_size, void* d_ws, size_t ws_size,
                              hipStream_t stream) {
    const float* x         = (const float*)d_in[0];
    const float* edge_attr = (const float*)d_in[2];
    const float* action    = (const float*)d_in[3];
    const int*   es        = (const int*)d_in[4];
    const int*   ed        = (const int*)d_in[5];
    const float* W1        = (const float*)d_in[6];
    const float* b1        = (const float*)d_in[7];
    const float* W2        = (const float*)d_in[8];
    const float* b2        = (const float*)d_in[9];
    const float* Wl        = (const float*)d_in[10];
    const float* bl        = (const float*)d_in[11];
    const float* Wv        = (const float*)d_in[12];
    const float* bv        = (const float*)d_in[13];
    float* out = (float*)d_out;
    int*   ws  = (int*)d_ws;

    build_csr<<<dim3(1), dim3(TPB), 0, stream>>>(es, ed, ws);
    critic_fused<<<dim3(out_size), dim3(TPB), 0, stream>>>(
        x, edge_attr, action, es, ed, W1, b1, W2, b2, Wl, bl, Wv, bv, ws, out);
}

// Round 12
// 128.778 us; speedup vs baseline: 1.1537x; 1.0261x over previous
//
#include <hip/hip_runtime.h>

// Problem constants
#define NNODES 64
#define HID 32
#define NFACT 3
#define NE 1024
#define NROWS (NE + NFACT)   // 1027
#define TPB 256
#define STR 36               // row stride (floats) for xpp/qp
#define MAXTILES 128         // capacity bound (true max = 124)
#define EPT (NE / TPB)       // 4 edges cached per thread

typedef short bf16x8 __attribute__((ext_vector_type(8)));
typedef float f32x4  __attribute__((ext_vector_type(4)));
typedef float f32x16 __attribute__((ext_vector_type(16)));

// round-to-nearest-even two fp32 -> packed bf16x2 (lo | hi<<16)
__device__ __forceinline__ unsigned pack_bf2(float lo, float hi) {
    unsigned ul = __builtin_bit_cast(unsigned, lo);
    unsigned uh = __builtin_bit_cast(unsigned, hi);
    ul += 0x7fffu + ((ul >> 16) & 1u);
    uh += 0x7fffu + ((uh >> 16) & 1u);
    return (ul >> 16) | (uh & 0xffff0000u);
}
__device__ __forceinline__ short f2bf(float f) {
    unsigned u = __builtin_bit_cast(unsigned, f);
    u += 0x7fffu + ((u >> 16) & 1u);
    return (short)(u >> 16);
}
__device__ __forceinline__ float4 fma4(float a, float4 w, float4 c) {
    c.x = fmaf(a, w.x, c.x); c.y = fmaf(a, w.y, c.y);
    c.z = fmaf(a, w.z, c.z); c.w = fmaf(a, w.w, c.w);
    return c;
}

// Single fused kernel: per-block in-LDS CSR build (kills the serialized 1-block
// build_csr dispatch, ~10us e2e) + factored critic with MFMA edge/head stages.
//   pep packed: low12 = edge id (0xFFF = pad), bits12-17 = dst node, bits18-23 = src node
__global__ __launch_bounds__(TPB, 4) void critic_fused(
    const float* __restrict__ x,
    const float* __restrict__ edge_attr,
    const float* __restrict__ action,
    const int*   __restrict__ es,
    const int*   __restrict__ ed,
    const float* __restrict__ W1,
    const float* __restrict__ b1,
    const float* __restrict__ W2,
    const float* __restrict__ b2,
    const float* __restrict__ Wl,
    const float* __restrict__ bl,
    const float* __restrict__ Wv,
    const float* __restrict__ bv,
    float* __restrict__ out)
{
    const int b    = blockIdx.x;
    const int tid  = threadIdx.x;
    const int lane = tid & 63;
    const int wv   = tid >> 6;
    const int quad = lane >> 4;
    const int m16  = lane & 15;
    const int kh   = quad * 8;

    __shared__ float4 xs4[NNODES];
    __shared__ float  xpp[NNODES * STR];
    __shared__ float  qp0[NNODES * STR];      // Q1 then P1
    __shared__ float  qp1[NNODES * STR];      // Q2 then P2
    __shared__ float  W1s[10 * HID];
    __shared__ float  b1s[HID];
    __shared__ float  wred[TPB / 64];
    // CSR tables (built per block)
    __shared__ int    sdeg[NNODES], soff[NNODES], scnt[NNODES];
    __shared__ int    tns[MAXTILES];
    __shared__ int    pep[MAXTILES * 16];
    __shared__ int    snt;

    // ---- Stage A: stage x + W1, zero xpp, init CSR tables ----
    if (tid < NNODES) { xs4[tid] = ((const float4*)x)[b * NNODES + tid]; sdeg[tid] = 0; scnt[tid] = 0; }
    if (tid < 80) ((float4*)W1s)[tid] = ((const float4*)W1)[tid];
    if (tid < HID) b1s[tid] = b1[tid];
    if (tid < MAXTILES) tns[tid] = 0;
#pragma unroll
    for (int i = 0; i < MAXTILES * 16 / TPB; i++) pep[tid + i * TPB] = 0xFFF;  // pad, node 0
#pragma unroll 1
    for (int i = tid; i < NNODES * STR; i += TPB) xpp[i] = 0.0f;

    // cache this thread's 4 edges in registers (coalesced global reads)
    int ces[EPT], ced[EPT];
#pragma unroll
    for (int i = 0; i < EPT; i++) {
        ces[i] = es[tid + i * TPB];
        ced[i] = ed[tid + i * TPB];
    }
    __syncthreads();

    // ---- CSR count + Stage Q (independent; co-scheduled to hide latency) ----
#pragma unroll
    for (int i = 0; i < EPT; i++) atomicAdd(&sdeg[ces[i]], 1);
    {
        const int n  = lane;
        const int k0 = wv * 8;
        const float4 xv = xs4[n];
        const float4* b1v = (const float4*)&b1s[k0];
        float4 q1a = b1v[0], q1b = b1v[1];
        float4 q2a = make_float4(0.f, 0.f, 0.f, 0.f), q2b = q2a;
#pragma unroll 1
        for (int i = 0; i < 4; i++) {
            const float xi = (i == 0) ? xv.x : (i == 1) ? xv.y : (i == 2) ? xv.z : xv.w;
            const float4* wa = (const float4*)&W1s[i * HID + k0];
            const float4* wb = (const float4*)&W1s[(4 + i) * HID + k0];
            q1a = fma4(xi, wa[0], q1a); q1b = fma4(xi, wa[1], q1b);
            q2a = fma4(xi, wb[0], q2a); q2b = fma4(xi, wb[1], q2b);
        }
        float4* q1w = (float4*)&qp0[n * STR + k0];
        float4* q2w = (float4*)&qp1[n * STR + k0];
        q1w[0] = q1a; q1w[1] = q1b;
        q2w[0] = q2a; q2w[1] = q2b;
    }
    __syncthreads();

    // ---- CSR scan (wave 0) ----
    if (tid < NNODES) {
        const int cnt = (sdeg[tid] + 15) >> 4;
        int scan = cnt;
#pragma unroll
        for (int o = 1; o < 64; o <<= 1) {
            const int v = __shfl_up(scan, o);
            if (tid >= o) scan += v;
        }
        soff[tid] = scan - cnt;
        if (tid == NNODES - 1) snt = scan;     // ntiles (~90-96, <=124)
    }
    __syncthreads();

    // ---- CSR pad fill (tile node ids; pads carry their tile's node) ----
    if (tid < NNODES) {
        const int base = soff[tid], cnt = (sdeg[tid] + 15) >> 4;
        const int padv = 0xFFF | (tid << 18);
#pragma unroll 1
        for (int j = 0; j < cnt; j++) {
            tns[base + j] = tid;
#pragma unroll 1
            for (int s = 0; s < 16; s++) pep[(base + j) * 16 + s] = padv;
        }
    }
    __syncthreads();

    // ---- CSR scatter (cached edges) ----
#pragma unroll
    for (int i = 0; i < EPT; i++) {
        const int n = ces[i];
        const int idx = atomicAdd(&scnt[n], 1);
        pep[soff[n] * 16 + idx] = (tid + i * TPB) | (ced[i] << 12) | (n << 18);
    }
    __syncthreads();

    // ---- Stage B: pair-tiled MFMA edge messages (32 edges / 2 nodes per iteration) ----
    {
        const float2* ea2 = (const float2*)edge_attr + (size_t)b * NE;
        const int NW  = TPB / 64;
        const int klo = (lane >> 5) * 8;      // this lane's K-slice base (0 or 8)
        const int n32 = lane & 31;

        const float4* w8l = (const float4*)&W1s[8 * HID + klo];
        const float4* w8h = (const float4*)&W1s[8 * HID + 16 + klo];
        const float4* w9l = (const float4*)&W1s[9 * HID + klo];
        const float4* w9h = (const float4*)&W1s[9 * HID + 16 + klo];
        const float4 w8a = w8l[0], w8b = w8l[1], w8c = w8h[0], w8d = w8h[1];
        const float4 w9a = w9l[0], w9b = w9l[1], w9c = w9h[0], w9d = w9h[1];

        bf16x8 bfA, bfB;   // W2 B-frags: B[k][n32], K-halves 0..15 / 16..31
#pragma unroll
        for (int j = 0; j < 8; j++) {
            bfA[j] = f2bf(W2[(klo + j) * HID + n32]);
            bfB[j] = f2bf(W2[(16 + klo + j) * HID + n32]);
        }

        const int np = (snt + 1) >> 1;

#pragma unroll 1
        for (int p = wv; p < np; p += NW) {
            const int raw = pep[p * 32 + n32];        // edge slot m = n32 of the pair
            const int tA  = tns[2 * p];
            const int tB  = tns[2 * p + 1];
            const int e    = raw & 0xFFF;
            const bool pad = (e == 0xFFF);
            const int d0   = (raw >> 12) & 63;
            const int nd   = (raw >> 18) & 63;        // src node of MY edge (gather)
            const float2 ea = ea2[pad ? 0 : e];

            const float4* A1 = (const float4*)&qp0[nd * STR + klo];
            const float4* A2 = (const float4*)&qp0[nd * STR + 16 + klo];
            const float4* G1 = (const float4*)&qp1[d0 * STR + klo];
            const float4* G2 = (const float4*)&qp1[d0 * STR + 16 + klo];
            const float4 a0 = A1[0], a1 = A1[1], a2 = A2[0], a3 = A2[1];
            const float4 g0 = G1[0], g1 = G1[1], g2 = G2[0], g3 = G2[1];

            const float hx0 = fmaxf(a0.x + g0.x + ea.x * w8a.x + ea.y * w9a.x, 0.f);
            const float hx1 = fmaxf(a0.y + g0.y + ea.x * w8a.y + ea.y * w9a.y, 0.f);
            const float hx2 = fmaxf(a0.z + g0.z + ea.x * w8a.z + ea.y * w9a.z, 0.f);
            const float hx3 = fmaxf(a0.w + g0.w + ea.x * w8a.w + ea.y * w9a.w, 0.f);
            const float hx4 = fmaxf(a1.x + g1.x + ea.x * w8b.x + ea.y * w9b.x, 0.f);
            const float hx5 = fmaxf(a1.y + g1.y + ea.x * w8b.y + ea.y * w9b.y, 0.f);
            const float hx6 = fmaxf(a1.z + g1.z + ea.x * w8b.z + ea.y * w9b.z, 0.f);
            const float hx7 = fmaxf(a1.w + g1.w + ea.x * w8b.w + ea.y * w9b.w, 0.f);
            const float hy0 = fmaxf(a2.x + g2.x + ea.x * w8c.x + ea.y * w9c.x, 0.f);
            const float hy1 = fmaxf(a2.y + g2.y + ea.x * w8c.y + ea.y * w9c.y, 0.f);
            const float hy2 = fmaxf(a2.z + g2.z + ea.x * w8c.z + ea.y * w9c.z, 0.f);
            const float hy3 = fmaxf(a2.w + g2.w + ea.x * w8c.w + ea.y * w9c.w, 0.f);
            const float hy4 = fmaxf(a3.x + g3.x + ea.x * w8d.x + ea.y * w9d.x, 0.f);
            const float hy5 = fmaxf(a3.y + g3.y + ea.x * w8d.y + ea.y * w9d.y, 0.f);
            const float hy6 = fmaxf(a3.z + g3.z + ea.x * w8d.z + ea.y * w9d.z, 0.f);
            const float hy7 = fmaxf(a3.w + g3.w + ea.x * w8d.w + ea.y * w9d.w, 0.f);

            uint4 pkA, pkB;
            pkA.x = pad ? 0u : pack_bf2(hx0, hx1);
            pkA.y = pad ? 0u : pack_bf2(hx2, hx3);
            pkA.z = pad ? 0u : pack_bf2(hx4, hx5);
            pkA.w = pad ? 0u : pack_bf2(hx6, hx7);
            pkB.x = pad ? 0u : pack_bf2(hy0, hy1);
            pkB.y = pad ? 0u : pack_bf2(hy2, hy3);
            pkB.z = pad ? 0u : pack_bf2(hy4, hy5);
            pkB.w = pad ? 0u : pack_bf2(hy6, hy7);
            const bf16x8 afA = __builtin_bit_cast(bf16x8, pkA);
            const bf16x8 afB = __builtin_bit_cast(bf16x8, pkB);

            f32x16 c;
#pragma unroll
            for (int j = 0; j < 16; j++) c[j] = 0.0f;
            c = __builtin_amdgcn_mfma_f32_32x32x16_bf16(afA, bfA, c, 0, 0, 0);
            c = __builtin_amdgcn_mfma_f32_32x32x16_bf16(afB, bfB, c, 0, 0, 0);

            // C: col=lane&31, row=(reg&3)+8*(reg>>2)+4*(lane>>5).
            // regs 0-7 -> rows 0-15 (tile A), regs 8-15 -> rows 16-31 (tile B).
            float sA = ((c[0] + c[1]) + (c[2] + c[3])) + ((c[4] + c[5]) + (c[6] + c[7]));
            float sB = ((c[8] + c[9]) + (c[10] + c[11])) + ((c[12] + c[13]) + (c[14] + c[15]));
            sA += __shfl_xor(sA, 32);
            sB += __shfl_xor(sB, 32);
            const int   nst = (lane < 32) ? tA : tB;
            const float sv  = (lane < 32) ? sA : sB;
            atomicAdd(&xpp[nst * STR + n32], sv);     // full wave, contiguous per node
        }
    }
    __syncthreads();

    // ---- Stage-P constants (loaded after B to keep stage-B VGPR peak low) ----
    bf16x8 bP1a, bP1b, bP2a, bP2b;    // Wl[4:36] / Wl[40:72] B-fragments, col halves
#pragma unroll
    for (int j = 0; j < 8; j++) {
        bP1a[j] = f2bf(Wl[(4 + kh + j) * HID + m16]);
        bP1b[j] = f2bf(Wl[(4 + kh + j) * HID + 16 + m16]);
        bP2a[j] = f2bf(Wl[(40 + kh + j) * HID + m16]);
        bP2b[j] = f2bf(Wl[(40 + kh + j) * HID + 16 + m16]);
    }
    float wx1a[4], wx1b[4], wx2a[4], wx2b[4];   // x-part weights (K=4 tail)
#pragma unroll
    for (int i = 0; i < 4; i++) {
        wx1a[i] = Wl[i * HID + m16];
        wx1b[i] = Wl[i * HID + 16 + m16];
        wx2a[i] = Wl[(36 + i) * HID + m16];
        wx2b[i] = Wl[(36 + i) * HID + 16 + m16];
    }
    const float blca = bl[m16], blcb = bl[16 + m16];
    float b2k[8];
#pragma unroll
    for (int j = 0; j < 8; j++) b2k[j] = b2[kh + j];
    const int   mrow = wv * 16 + m16;                // A-row this lane owns in stage P
    const float dn   = (float)sdeg[mrow];

    // ---- Stage P: head projections via MFMA ----
    {
        const float4* xr = (const float4*)&xpp[mrow * STR + kh];
        float4 x0 = xr[0], x1 = xr[1];
        x0.x = fmaf(dn, b2k[0], x0.x); x0.y = fmaf(dn, b2k[1], x0.y);
        x0.z = fmaf(dn, b2k[2], x0.z); x0.w = fmaf(dn, b2k[3], x0.w);
        x1.x = fmaf(dn, b2k[4], x1.x); x1.y = fmaf(dn, b2k[5], x1.y);
        x1.z = fmaf(dn, b2k[6], x1.z); x1.w = fmaf(dn, b2k[7], x1.w);
        uint4 packed;
        packed.x = pack_bf2(x0.x, x0.y);
        packed.y = pack_bf2(x0.z, x0.w);
        packed.z = pack_bf2(x1.x, x1.y);
        packed.w = pack_bf2(x1.z, x1.w);
        const bf16x8 af = __builtin_bit_cast(bf16x8, packed);

        f32x4 c1a, c1b, c2a, c2b;
#pragma unroll
        for (int r = 0; r < 4; r++) {
            const float4 xv = xs4[wv * 16 + quad * 4 + r];
            float a0 = blca, a1 = blcb, a2 = 0.f, a3 = 0.f;
#pragma unroll
            for (int i = 0; i < 4; i++) {
                const float xi = (i == 0) ? xv.x : (i == 1) ? xv.y : (i == 2) ? xv.z : xv.w;
                a0 = fmaf(xi, wx1a[i], a0);
                a1 = fmaf(xi, wx1b[i], a1);
                a2 = fmaf(xi, wx2a[i], a2);
                a3 = fmaf(xi, wx2b[i], a3);
            }
            c1a[r] = a0; c1b[r] = a1; c2a[r] = a2; c2b[r] = a3;
        }
        c1a = __builtin_amdgcn_mfma_f32_16x16x32_bf16(af, bP1a, c1a, 0, 0, 0);
        c1b = __builtin_amdgcn_mfma_f32_16x16x32_bf16(af, bP1b, c1b, 0, 0, 0);
        c2a = __builtin_amdgcn_mfma_f32_16x16x32_bf16(af, bP2a, c2a, 0, 0, 0);
        c2b = __builtin_amdgcn_mfma_f32_16x16x32_bf16(af, bP2b, c2b, 0, 0, 0);

        // C layout: row = wv*16 + quad*4 + r, col = m16 / 16+m16
#pragma unroll
        for (int r = 0; r < 4; r++) {
            const int row = wv * 16 + quad * 4 + r;
            qp0[row * STR + m16]      = c1a[r];
            qp0[row * STR + 16 + m16] = c1b[r];
            qp1[row * STR + m16]      = c2a[r];
            qp1[row * STR + 16 + m16] = c2b[r];
        }
    }
    __syncthreads();

    // ---- Stage C: per-row combine + value head ----
    float vsum = 0.0f;
    {
        const float* actb = action + (size_t)b * NROWS;
        const float bvv = bv[0];
        const float* Wl72 = Wl + 72 * HID;   // loop-invariant s_loads, hoisted
#pragma unroll 1
        for (int i = 0; i < 4; i++) {
            const int na = ces[i], nb = ced[i];           // cached edge endpoints
            const float a = actb[tid + i * TPB];
            const float4* p1v = (const float4*)&qp0[na * STR];
            const float4* p2v = (const float4*)&qp1[nb * STR];
            float v0 = bvv, v1 = 0.0f;
#pragma unroll 1
            for (int q = 0; q < 8; q += 2) {
                const float4 pa0 = p1v[q],     pb0 = p2v[q];
                const float4 pa1 = p1v[q + 1], pb1 = p2v[q + 1];
                const int k = q * 4;
                v0 += fmaxf(pa0.x + pb0.x + a * Wl72[k+0], 0.f) * Wv[k+0];
                v1 += fmaxf(pa0.y + pb0.y + a * Wl72[k+1], 0.f) * Wv[k+1];
                v0 += fmaxf(pa0.z + pb0.z + a * Wl72[k+2], 0.f) * Wv[k+2];
                v1 += fmaxf(pa0.w + pb0.w + a * Wl72[k+3], 0.f) * Wv[k+3];
                v0 += fmaxf(pa1.x + pb1.x + a * Wl72[k+4], 0.f) * Wv[k+4];
                v1 += fmaxf(pa1.y + pb1.y + a * Wl72[k+5], 0.f) * Wv[k+5];
                v0 += fmaxf(pa1.z + pb1.z + a * Wl72[k+6], 0.f) * Wv[k+6];
                v1 += fmaxf(pa1.w + pb1.w + a * Wl72[k+7], 0.f) * Wv[k+7];
            }
            vsum += v0 + v1;
        }
        // factory rows 1024..1026 (na == nb)
        if (tid < NFACT) {
            const int r = NE + tid;
            const int na = NNODES - NFACT + tid;
            const float a = actb[r];
            const float4* p1v = (const float4*)&qp0[na * STR];
            const float4* p2v = (const float4*)&qp1[na * STR];
            float v = bvv;
#pragma unroll 1
            for (int q = 0; q < 8; q++) {
                const float4 pa = p1v[q], pb = p2v[q];
                const int k = q * 4;
                v += fmaxf(pa.x + pb.x + a * Wl72[k+0], 0.f) * Wv[k+0];
                v += fmaxf(pa.y + pb.y + a * Wl72[k+1], 0.f) * Wv[k+1];
                v += fmaxf(pa.z + pb.z + a * Wl72[k+2], 0.f) * Wv[k+2];
                v += fmaxf(pa.w + pb.w + a * Wl72[k+3], 0.f) * Wv[k+3];
            }
            vsum += v;
        }
    }

    // ---- block reduction ----
#pragma unroll
    for (int off = 32; off > 0; off >>= 1)
        vsum += __shfl_down(vsum, off, 64);
    if ((tid & 63) == 0) wred[tid >> 6] = vsum;
    __syncthreads();
    if (tid == 0) {
        float t = 0.0f;
#pragma unroll
        for (int w = 0; w < TPB / 64; w++) t += wred[w];
        out[b] = t;
    }
}

extern "C" void kernel_launch(void* const* d_in, const int* in_sizes, int n_in,
                              void* d_out, int out_size, void* d_ws, size_t ws_size,
                              hipStream_t stream) {
    const float* x         = (const float*)d_in[0];
    const float* edge_attr = (const float*)d_in[2];
    const float* action    = (const float*)d_in[3];
    const int*   es        = (const int*)d_in[4];
    const int*   ed        = (const int*)d_in[5];
    const float* W1        = (const float*)d_in[6];
    const float* b1        = (const float*)d_in[7];
    const float* W2        = (const float*)d_in[8];
    const float* b2        = (const float*)d_in[9];
    const float* Wl        = (const float*)d_in[10];
    const float* bl        = (const float*)d_in[11];
    const float* Wv        = (const float*)d_in[12];
    const float* bv        = (const float*)d_in[13];
    float* out = (float*)d_out;

    critic_fused<<<dim3(out_size), dim3(TPB), 0, stream>>>(
        x, edge_attr, action, es, ed, W1, b1, W2, b2, Wl, bl, Wv, bv, out);
}